// Round 9
// baseline (315.262 us; speedup 1.0000x reference)
//
#include <hip/hip_runtime.h>
#include <cstddef>
#include <cstdint>

#define B_DIM 4
#define T_DIM 1024
#define D_DIM 1024
#define H_DIM 16
#define DH 64
#define JDIM 2048
#define MEMLEN 1024
#define RELPAD 2176  // 2048 + 128 zero rows for banded-GEMM overrun

typedef float floatx4 __attribute__((ext_vector_type(4)));
typedef short short8 __attribute__((ext_vector_type(8)));

static __device__ __forceinline__ short f2bf(float f) {
    union { float f; uint32_t u; } v; v.f = f;
    uint32_t r = (v.u + 0x7FFFu + ((v.u >> 16) & 1u)) >> 16;
    return (short)r;
}

// async global->LDS, 16B per lane; LDS dest = wave-uniform base + lane*16
static __device__ __forceinline__ void gl_lds16(const short* g, short* l) {
    __builtin_amdgcn_global_load_lds(
        (const __attribute__((address_space(1))) void*)g,
        (__attribute__((address_space(3))) void*)l, 16, 0, 0);
}

// DPP-based fmax with a cross-lane source (VALU pipe, no LDS)
template <int CTRL>
static __device__ __forceinline__ float dpp_fmax(float v) {
    int y = __builtin_amdgcn_update_dpp(0, __builtin_bit_cast(int, v),
                                        CTRL, 0xF, 0xF, true);
    return fmaxf(v, __builtin_bit_cast(float, y));
}
static __device__ __forceinline__ float row16_max(float v) {
    v = dpp_fmax<0xB1>(v);    // quad_perm xor1
    v = dpp_fmax<0x4E>(v);    // quad_perm xor2
    v = dpp_fmax<0x124>(v);   // row_ror:4
    v = dpp_fmax<0x128>(v);   // row_ror:8
    return v;
}

// ---------------------------------------------------------------------------
// Merged prep: three independent jobs routed by blockIdx.x (block-uniform
// branch, so the transpose's __syncthreads is legal).
//   [0,8192):       mem_next = x; kvb = bf16(concat(mem, x))
//   [8192,14336):   weight transposes wq/wkv/wo -> wkvqT/woT
//   [14336,16512):  rel_w -> relb bf16 [h][jp][c] padded
// ---------------------------------------------------------------------------
__global__ __launch_bounds__(256) void prep_all(
    const float* __restrict__ x, const float* __restrict__ mem,
    const float* __restrict__ rel,
    float* __restrict__ mem_next, short* __restrict__ kvb,
    const float* __restrict__ wq, const float* __restrict__ wkv,
    const float* __restrict__ wo, short* __restrict__ wkvqT,
    short* __restrict__ woT, short* __restrict__ relb) {
    __shared__ float tile[32][33];
    const int bx = blockIdx.x;
    const int tid = threadIdx.x;

    if (bx < 8192) {
        // ---- prep_xmem ----
        const size_t gid = (size_t)bx * 256 + tid;
        if (gid < 1048576) {
            const size_t idx = gid * 4;
            float4 v = *(const float4*)(x + idx);
            *(float4*)(mem_next + idx) = v;
            const int b = (int)(idx >> 20);
            const size_t r = idx & 1048575;
            short4 o;
            o.x = f2bf(v.x); o.y = f2bf(v.y); o.z = f2bf(v.z); o.w = f2bf(v.w);
            *(short4*)(kvb + (size_t)b * 2097152 + 1048576 + r) = o;
        } else {
            const size_t idx = (gid - 1048576) * 4;
            float4 v = *(const float4*)(mem + idx);
            const int b = (int)(idx >> 20);
            const size_t r = idx & 1048575;
            short4 o;
            o.x = f2bf(v.x); o.y = f2bf(v.y); o.z = f2bf(v.z); o.w = f2bf(v.w);
            *(short4*)(kvb + (size_t)b * 2097152 + r) = o;
        }
    } else if (bx < 14336) {
        // ---- transpose_w3: i = z*2048 + gy*32 + gx ----
        const int i = bx - 8192;
        const int z = i >> 11;
        const int rem = i & 2047;
        const int gx = rem & 31, gy = rem >> 5;
        const int N = (z == 1) ? 2048 : 1024;
        if (gy * 32 >= N) return;
        const float* w = (z == 0) ? wq : (z == 1) ? wkv : wo;
        short* wT = (z == 0) ? (wkvqT + (size_t)2048 * 1024) : (z == 1) ? wkvqT : woT;
        const int k0 = gx * 32, n0 = gy * 32;
        const int tx = tid & 31, ty = tid >> 5;
        for (int r = ty; r < 32; r += 8)
            tile[r][tx] = w[(size_t)(k0 + r) * N + n0 + tx];
        __syncthreads();
        for (int r = ty; r < 32; r += 8)
            wT[(size_t)(n0 + r) * 1024 + k0 + tx] = f2bf(tile[tx][r]);
    } else {
        // ---- convert_rel: i = gy*136 + gx ----
        const int i = bx - 14336;
        const int gx = i % 136, gy = i / 136;
        const int h = gy;
        const int jp = gx * 16 + (tid >> 4);
        const int c = (tid & 15) << 2;
        float4 v = make_float4(0.f, 0.f, 0.f, 0.f);
        if (jp < JDIM) v = *(const float4*)(rel + ((size_t)jp * H_DIM + h) * DH + c);
        short4 o;
        o.x = f2bf(v.x); o.y = f2bf(v.y); o.z = f2bf(v.z); o.w = f2bf(v.w);
        *(short4*)(relb + ((size_t)h * RELPAD + jp) * DH + c) = o;
    }
}

// ---------------------------------------------------------------------------
// bf16 MFMA GEMM v2: 128x128 tile, BK=32, 256 threads, DOUBLE-BUFFERED LDS
// with stage-before-compute and ONE barrier per K-iter (T3 minimum 2-phase
// recipe). Old loop was {barrier; issue; barrier+drain; compute} — the drain
// immediately after issue exposed the full load latency every iteration
// (measured MfmaUtil ~4.4%). New loop: {issue stage(t+1) -> buf^1; compute
// buf; __syncthreads (auto vmcnt(0) drains the prefetch — cover = the whole
// compute phase)}. Race-safe: buf[nxt] writes are disjoint from buf[cur]
// reads; prior reads of buf[nxt] completed before the barrier preceding the
// stage. LDS 32 KB -> 5 blocks/CU = exactly the 1280-block grid (resident,
// balanced). Math bit-identical.
// CMODE 1 (fused kvq): Bt = wkvqT [3072][1024], grid (24, 64).
//   col<1024 -> kb [bh][j][c]; col<2048 -> vTb [bh][c][j];
//   col>=2048 -> qb [bh][i][c] PRE-SCALED by 0.125*log2e, x-half rows only.
// CMODE 2: out = A @ Bt^T + bias -> Cf fp32 [r][n].
// ---------------------------------------------------------------------------
template <int CMODE>
__global__ __launch_bounds__(256) void mfma_gemm(
    const short* __restrict__ A, const short* __restrict__ Bt,
    const float* __restrict__ bias,
    short* __restrict__ C0, short* __restrict__ C1, short* __restrict__ C2,
    float* __restrict__ Cf) {
    constexpr int K = 1024;
    constexpr int NT = K / 32;  // 32 K-steps
    const int row0 = blockIdx.y << 7, col0 = blockIdx.x << 7;
    if (CMODE == 1 && col0 >= 2048 && (row0 & 2047) < 1024) return;  // q x mem-rows

    __shared__ short ash[2][128 * 32];
    __shared__ short bsh[2][128 * 32];

    const int tid = threadIdx.x;
    const int w = tid >> 6, lane = tid & 63;
    const int l15 = lane & 15, quad = lane >> 4;
    const int wr = w >> 1, wc = w & 1;

    const int sk = (lane & 3) << 3;
    const short* ap0 = A + (size_t)(row0 + (w << 5) + (lane >> 2)) * K + sk;
    const short* ap1 = ap0 + (size_t)16 * K;
    const short* bp0 = Bt + (size_t)(col0 + (w << 5) + (lane >> 2)) * K + sk;
    const short* bp1 = bp0 + (size_t)16 * K;

    // prologue: stage t=0 into buf 0
    gl_lds16(ap0, ash[0] + (w << 10));
    gl_lds16(ap1, ash[0] + (w << 10) + 512);
    gl_lds16(bp0, bsh[0] + (w << 10));
    gl_lds16(bp1, bsh[0] + (w << 10) + 512);
    __syncthreads();  // drains stage(0)

    floatx4 acc[4][4] = {};

#pragma unroll 2
    for (int t = 0; t < NT; ++t) {
        const int cur = t & 1;
        if (t + 1 < NT) {  // issue stage(t+1) BEFORE compute: full-phase cover
            const int nxt = cur ^ 1;
            const int k1 = (t + 1) << 5;
            gl_lds16(ap0 + k1, ash[nxt] + (w << 10));
            gl_lds16(ap1 + k1, ash[nxt] + (w << 10) + 512);
            gl_lds16(bp0 + k1, bsh[nxt] + (w << 10));
            gl_lds16(bp1 + k1, bsh[nxt] + (w << 10) + 512);
        }

        short8 af[4];
#pragma unroll
        for (int mt = 0; mt < 4; ++mt)
            af[mt] = *(const short8*)&ash[cur][(((wr << 6) + (mt << 4) + l15) << 5) + (quad << 3)];
#pragma unroll
        for (int nt = 0; nt < 4; ++nt) {
            short8 bf = *(const short8*)&bsh[cur][(((wc << 6) + (nt << 4) + l15) << 5) + (quad << 3)];
#pragma unroll
            for (int mt = 0; mt < 4; ++mt)
                acc[mt][nt] = __builtin_amdgcn_mfma_f32_16x16x32_bf16(af[mt], bf, acc[mt][nt], 0, 0, 0);
        }
        __syncthreads();  // drains stage(t+1); publishes buf[nxt]; frees buf[cur]
    }

#pragma unroll
    for (int nt = 0; nt < 4; ++nt) {
        const int col = col0 + (wc << 6) + (nt << 4) + l15;
        float bv = (CMODE == 2) ? bias[col] : 0.f;
#pragma unroll
        for (int mt = 0; mt < 4; ++mt) {
#pragma unroll
            for (int rr = 0; rr < 4; ++rr) {
                const int row = row0 + (wr << 6) + (mt << 4) + (quad << 2) + rr;
                const float val = acc[mt][nt][rr];
                if (CMODE == 1) {
                    int b = row >> 11, j = row & 2047;
                    if (col < 1024) {
                        int h = col >> 6, c = col & 63;
                        C0[(((size_t)b * H_DIM + h) * JDIM + j) * DH + c] = f2bf(val);
                    } else if (col < 2048) {
                        int n2 = col - 1024, h = n2 >> 6, c = n2 & 63;
                        C1[(((size_t)b * H_DIM + h) * DH + c) * JDIM + j] = f2bf(val);
                    } else {
                        int n2 = col - 2048, h = n2 >> 6, c = n2 & 63;
                        int i = j - 1024;  // guaranteed >= 0 by early-exit
                        // pre-scale q by 0.125 * log2(e): QK^T and rel-G come
                        // out of MFMA already in the exp2 domain
                        C2[(((size_t)b * H_DIM + h) * T_DIM + i) * DH + c] =
                            f2bf(val * 0.18033688f);
                    }
                } else {
                    Cf[(size_t)row * 1024 + col] = val + bv;
                }
            }
        }
    }
}

// ---------------------------------------------------------------------------
// Flash attention v9 (unchanged from round 8): 2 barriers/iter, K/V single-
// buffer + mod-3 rel ring, psh overlaid in dead s0 slot w/ XOR swizzle,
// prescaled q, defer-max, balanced i-tile map, 40 KB LDS -> 4 blocks/CU,
// setprio around MFMA clusters, v_perm rel pack/gather.
// ---------------------------------------------------------------------------
__global__ __launch_bounds__(256, 4) void flash_attn(
    const short* __restrict__ qb, const short* __restrict__ kb,
    const short* __restrict__ vTb, const short* __restrict__ relb,
    short* __restrict__ ob) {
    __shared__ short kshf[8 * 512];       // 8 KB
    __shared__ short vshf[8 * 512];       // 8 KB
    __shared__ short rshf[3 * 8 * 512];   // 24 KB, 3-seg ring (64 rows/seg);
                                          // psh overlays the dead s0 slot

    const int tid = threadIdx.x;
    const int w = tid >> 6;
    const int lane = tid & 63;
    const int l15 = lane & 15, quad = lane >> 4;
    const int bh = blockIdx.y, h = bh & 15, b = bh >> 4;
    // balanced i-tile map: co-resident quads get itiles {b,b+4,b+8,b+12}
    const int xt = blockIdx.x;
    const int itile = ((xt >> 2) + ((xt & 3) << 2) + (((blockIdx.y >> 4) & 3) << 2)) & 15;
    const int i0 = itile << 6;
    const int goff = 3 - w;

    const short* kb_b = kb + (size_t)bh * JDIM * DH;
    const short* vT_b = vTb + (size_t)bh * DH * JDIM;
    const short* rel_b = relb + (size_t)h * RELPAD * DH;

    // Q fragments straight from global (pre-scaled by 0.125*log2e)
    const short* qrow = qb + ((size_t)bh * T_DIM + i0 + (w << 4) + l15) * DH;
    const short8 a_q0 = *(const short8*)(qrow + (quad << 3));
    const short8 a_q1 = *(const short8*)(qrow + 32 + (quad << 3));

    // staging pointers: wave w owns chunks {w, w+4} of each tile
    const int kc0 = w, kc1 = w + 4;
    const short* kp0 = kb_b + (size_t)(((kc0 >> 1) << 4) + l15) * DH + (kc0 & 1) * 32 + (quad << 3);
    const short* kp1 = kb_b + (size_t)(((kc1 >> 1) << 4) + l15) * DH + (kc1 & 1) * 32 + (quad << 3);
    const short* vp0 = vT_b + (size_t)(((kc0 >> 1) << 4) + l15) * JDIM + (kc0 & 1) * 32 + (quad << 3);
    const short* vp1 = vT_b + (size_t)(((kc1 >> 1) << 4) + l15) * JDIM + (kc1 & 1) * 32 + (quad << 3);
    const int base00 = 960 - i0;  // >= 0

    // ---- prologue: K(0), V(0), rel segs 0,1 (128 rows) ----
    gl_lds16(kp0, kshf + (kc0 << 9));
    gl_lds16(kp1, kshf + (kc1 << 9));
    gl_lds16(vp0, vshf + (kc0 << 9));
    gl_lds16(vp1, vshf + (kc1 << 9));
    kp0 += 64 * DH; kp1 += 64 * DH; vp0 += 64; vp1 += 64;
#pragma unroll
    for (int s = 0; s < 4; ++s) {
        const int c4 = w + (s << 2);  // chunk over segs 0..1 (contiguous)
        const short* rp = rel_b + (size_t)(base00 + ((c4 >> 1) << 4) + l15) * DH +
                          (c4 & 1) * 32 + (quad << 3);
        gl_lds16(rp, rshf + (c4 << 9));
    }
    // steady-state rel write pointers (rows base0+128.., chunks w, w+4 of seg s2)
    const short* rw0 = rel_b + (size_t)(base00 + 128 + ((w >> 1) << 4) + l15) * DH +
                       (w & 1) * 32 + (quad << 3);
    const short* rw1 = rel_b + (size_t)(base00 + 128 + (((w + 4) >> 1) << 4) + l15) * DH +
                       ((w + 4) & 1) * 32 + (quad << 3);
    __syncthreads();  // drain prologue

    // all-ones B fragment for row-sum MFMA
    short8 ones8;
#pragma unroll
    for (int z = 0; z < 8; ++z) ones8[z] = (short)0x3F80;

    // gather controls: source lane + v_perm selector
    int srcl[4];
    uint32_t psel[4];
#pragma unroll
    for (int r = 0; r < 4; ++r) {
        const int t = l15 - (quad << 2) - r + 15;
        psel[r] = (t >> 4) ? 0x01000404u : 0x03020404u;
        srcl[r] = (quad << 4) | (t & 15);
    }

    floatx4 o_acc[4] = {};
    float m_r[4], l_r[4];
#pragma unroll
    for (int r = 0; r < 4; ++r) { m_r[r] = -3.0e38f; l_r[r] = 0.f; }

    const int jt_end = itile + 17;
    int s0 = 0, s1 = 1, s2 = 2;    // ring segs: jt, jt+1, prefetch target

    for (int jt = 0; jt < jt_end; ++jt) {
        // ---- QK^T + banded rel (MFMA cluster, prio-boosted) ----
        __builtin_amdgcn_s_setprio(1);
        floatx4 s_acc[4];
#pragma unroll
        for (int nt = 0; nt < 4; ++nt) {
            short8 bk0 = *(const short8*)&kshf[((nt << 1) << 9) + (lane << 3)];
            short8 bk1 = *(const short8*)&kshf[(((nt << 1) + 1) << 9) + (lane << 3)];
            floatx4 acc = {0.f, 0.f, 0.f, 0.f};
            acc = __builtin_amdgcn_mfma_f32_16x16x32_bf16(a_q0, bk0, acc, 0, 0, 0);
            acc = __builtin_amdgcn_mfma_f32_16x16x32_bf16(a_q1, bk1, acc, 0, 0, 0);
            s_acc[nt] = acc;
        }

        // G blocks rb = gi+goff, gi in [0,5); ring seg by rb>=4
        floatx4 G[5];
#pragma unroll
        for (int gi = 0; gi < 5; ++gi) {
            const int rb = gi + goff;
            const int seg = (rb & 4) ? s1 : s0;
            const int ch = (seg << 3) + ((rb & 3) << 1);
            short8 br0 = *(const short8*)&rshf[(ch << 9) + (lane << 3)];
            short8 br1 = *(const short8*)&rshf[((ch + 1) << 9) + (lane << 3)];
            floatx4 acc = {0.f, 0.f, 0.f, 0.f};
            acc = __builtin_amdgcn_mfma_f32_16x16x32_bf16(a_q0, br0, acc, 0, 0, 0);
            G[gi] = __builtin_amdgcn_mfma_f32_16x16x32_bf16(a_q1, br1, acc, 0, 0, 0);
        }
        __builtin_amdgcn_s_setprio(0);

        // ---- pack + gather shifted rel (v_perm: 1 op each) ----
        uint32_t pk[4][4];
#pragma unroll
        for (int gi = 0; gi < 4; ++gi)
#pragma unroll
            for (int r = 0; r < 4; ++r)
                pk[gi][r] = __builtin_amdgcn_perm(
                    __builtin_bit_cast(uint32_t, G[gi][r]),
                    __builtin_bit_cast(uint32_t, G[gi + 1][r]), 0x07060302u);
#pragma unroll
        for (int nt = 0; nt < 4; ++nt)
#pragma unroll
            for (int r = 0; r < 4; ++r) {
                uint32_t pv = (uint32_t)__shfl((int)pk[nt][r], srcl[r], 64);
                uint32_t gb = __builtin_amdgcn_perm(0u, pv, psel[r]);
                s_acc[nt][r] = s_acc[nt][r] + __builtin_bit_cast(float, gb);
            }
        if (jt == jt_end - 1) {  // triangular mask: valid iff u <= v
#pragma unroll
            for (int nt = 0; nt < 4; ++nt) {
                const int u = (nt << 4) + l15;
#pragma unroll
                for (int r = 0; r < 4; ++r) {
                    const int v = (w << 4) + (quad << 2) + r;
                    if (u > v) s_acc[nt][r] = -3.0e38f;
                }
            }
        }

        __syncthreads();  // b1: drains V(jt); seg s0 rel data now dead -> psh
        if (jt + 1 < jt_end) {  // prefetch K(jt+1), rel seg s2 (drained at b2)
            gl_lds16(kp0, kshf + (kc0 << 9));
            gl_lds16(kp1, kshf + (kc1 << 9));
            gl_lds16(rw0, rshf + (s2 << 12) + (w << 9));
            gl_lds16(rw1, rshf + (s2 << 12) + ((w + 4) << 9));
            kp0 += 64 * DH; kp1 += 64 * DH; rw0 += 64 * DH; rw1 += 64 * DH;
        }

        // psh lives in the dead s0 slot this iteration (wave-private rows)
        short* pshp = rshf + (s0 << 12);

        // ---- online softmax with defer-max (THR=8) ----
        float tm[4];
        bool need = false;
#pragma unroll
        for (int r = 0; r < 4; ++r) {
            tm[r] = fmaxf(fmaxf(s_acc[0][r], s_acc[1][r]),
                          fmaxf(s_acc[2][r], s_acc[3][r]));
            need |= (tm[r] > m_r[r] + 8.0f);
        }
        if (__any((int)need)) {
#pragma unroll
            for (int r = 0; r < 4; ++r) {
                const float t = row16_max(tm[r]);
                const float mx = fmaxf(m_r[r], t);
                const float alpha = __builtin_amdgcn_exp2f(m_r[r] - mx);
                m_r[r] = mx;
                l_r[r] *= alpha;
#pragma unroll
                for (int ct = 0; ct < 4; ++ct) o_acc[ct][r] *= alpha;
            }
        }
#pragma unroll
        for (int r = 0; r < 4; ++r) {
            const int prow = (w << 4) + (quad << 2) + r;
            char* rowb = (char*)pshp + (prow << 7);   // 128 B row stride
            const int swz = (prow & 7) << 4;          // XOR bank swizzle
#pragma unroll
            for (int nt = 0; nt < 4; ++nt) {
                const float p = __builtin_amdgcn_exp2f(s_acc[nt][r] - m_r[r]);
                *(short*)(rowb + ((((nt << 5) + (l15 << 1))) ^ swz)) = f2bf(p);
            }
        }

        // ---- PV + row-sum (MFMA cluster, prio-boosted; V(jt) drained at b1)
        const int arow = (w << 4) + l15;
        const char* arowb = (const char*)pshp + (arow << 7);
        const int asw = (l15 & 7) << 4;
        const short8 a_p0 = *(const short8*)(arowb + ((quad << 4) ^ asw));
        const short8 a_p1 = *(const short8*)(arowb + ((64 + (quad << 4)) ^ asw));
        __builtin_amdgcn_s_setprio(1);
        floatx4 ls = {0.f, 0.f, 0.f, 0.f};
        ls = __builtin_amdgcn_mfma_f32_16x16x32_bf16(a_p0, ones8, ls, 0, 0, 0);
        ls = __builtin_amdgcn_mfma_f32_16x16x32_bf16(a_p1, ones8, ls, 0, 0, 0);
#pragma unroll
        for (int r = 0; r < 4; ++r) l_r[r] += ls[r];
#pragma unroll
        for (int ct = 0; ct < 4; ++ct) {
            short8 bv0 = *(const short8*)&vshf[((ct << 1) << 9) + (lane << 3)];
            short8 bv1 = *(const short8*)&vshf[(((ct << 1) + 1) << 9) + (lane << 3)];
            o_acc[ct] = __builtin_amdgcn_mfma_f32_16x16x32_bf16(a_p0, bv0, o_acc[ct], 0, 0, 0);
            o_acc[ct] = __builtin_amdgcn_mfma_f32_16x16x32_bf16(a_p1, bv1, o_acc[ct], 0, 0, 0);
        }
        __builtin_amdgcn_s_setprio(0);

        __syncthreads();  // b2: drains K(jt+1)/rel; V buffer free; psh dead
        if (jt + 1 < jt_end) {  // prefetch V(jt+1) (drained at b1 of jt+1)
            gl_lds16(vp0, vshf + (kc0 << 9));
            gl_lds16(vp1, vshf + (kc1 << 9));
            vp0 += 64; vp1 += 64;
        }
        const int t = s0; s0 = s1; s1 = s2; s2 = t;  // rotate ring
    }

    // ---- epilogue: normalize, write ob bf16 [b][i][d] ----
#pragma unroll
    for (int ct = 0; ct < 4; ++ct) {
#pragma unroll
        for (int r = 0; r < 4; ++r) {
            const int i = i0 + (w << 4) + (quad << 2) + r;
            const float val = o_acc[ct][r] / l_r[r];
            ob[((size_t)b * T_DIM + i) * D_DIM + h * DH + (ct << 4) + l15] = f2bf(val);
        }
    }
}

// ---------------------------------------------------------------------------
extern "C" void kernel_launch(void* const* d_in, const int* in_sizes, int n_in,
                              void* d_out, int out_size, void* d_ws, size_t ws_size,
                              hipStream_t stream) {
    const float* x = (const float*)d_in[0];
    const float* mem = (const float*)d_in[1];
    const float* wq = (const float*)d_in[2];
    const float* wkv = (const float*)d_in[3];
    const float* wo = (const float*)d_in[4];
    const float* bo = (const float*)d_in[5];
    const float* rel_w = (const float*)d_in[6];

    float* out = (float*)d_out;
    float* mem_next = out + (size_t)B_DIM * T_DIM * D_DIM;

    // workspace layout (shorts), ~80 MB total
    short* kvb = (short*)d_ws;       // 8,388,608  [b][j][d] bf16
    short* qb = kvb + 8388608;       // 4,194,304  [bh][i][c]
    short* kb = qb + 4194304;        // 8,388,608  [bh][j][c]
    short* vTb = kb + 8388608;       // 8,388,608  [bh][c][j]
    short* relb = vTb + 8388608;     // 2,228,224  [h][jp][c]
    short* ob = relb + 2228224;      // 4,194,304  [b*i][d]
    short* wkvqT = ob + 4194304;     // 3,145,728  [3072][1024]
    short* woT = wkvqT + 3145728;    // 1,048,576  [1024][1024]

    // merged prep: mem_next/kvb + weight transposes + rel conversion
    hipLaunchKernelGGL(prep_all, dim3(16512), dim3(256), 0, stream,
                       x, mem, rel_w, mem_next, kvb, wq, wkv, wo,
                       wkvqT, woT, relb);

    // fused kvq GEMM: kvin @ [wkv|wq] -> kb, vTb, qb
    hipLaunchKernelGGL((mfma_gemm<1>), dim3(24, 64), dim3(256), 0, stream,
                       kvb, wkvqT, nullptr, kb, vTb, qb, nullptr);

    // flash attention -> ob bf16
    hipLaunchKernelGGL(flash_attn, dim3(16, 64), dim3(256), 0, stream,
                       qb, kb, vTb, relb, ob);

    // out = ob @ wo + bo -> fp32
    hipLaunchKernelGGL((mfma_gemm<2>), dim3(8, 32), dim3(256), 0, stream,
                       ob, woT, bo, nullptr, nullptr, nullptr, out);
}

// Round 10
// 312.725 us; speedup vs baseline: 1.0081x; 1.0081x over previous
//
#include <hip/hip_runtime.h>
#include <cstddef>
#include <cstdint>

#define B_DIM 4
#define T_DIM 1024
#define D_DIM 1024
#define H_DIM 16
#define DH 64
#define JDIM 2048
#define MEMLEN 1024
#define RELPAD 2176  // 2048 + 128 zero rows for banded-GEMM overrun

typedef float floatx4 __attribute__((ext_vector_type(4)));
typedef short short8 __attribute__((ext_vector_type(8)));

static __device__ __forceinline__ short f2bf(float f) {
    union { float f; uint32_t u; } v; v.f = f;
    uint32_t r = (v.u + 0x7FFFu + ((v.u >> 16) & 1u)) >> 16;
    return (short)r;
}

// async global->LDS, 16B per lane; LDS dest = wave-uniform base + lane*16
static __device__ __forceinline__ void gl_lds16(const short* g, short* l) {
    __builtin_amdgcn_global_load_lds(
        (const __attribute__((address_space(1))) void*)g,
        (__attribute__((address_space(3))) void*)l, 16, 0, 0);
}

// DPP-based fmax with a cross-lane source (VALU pipe, no LDS)
template <int CTRL>
static __device__ __forceinline__ float dpp_fmax(float v) {
    int y = __builtin_amdgcn_update_dpp(0, __builtin_bit_cast(int, v),
                                        CTRL, 0xF, 0xF, true);
    return fmaxf(v, __builtin_bit_cast(float, y));
}
static __device__ __forceinline__ float row16_max(float v) {
    v = dpp_fmax<0xB1>(v);    // quad_perm xor1
    v = dpp_fmax<0x4E>(v);    // quad_perm xor2
    v = dpp_fmax<0x124>(v);   // row_ror:4
    v = dpp_fmax<0x128>(v);   // row_ror:8
    return v;
}

// ---------------------------------------------------------------------------
// Merged prep: three independent jobs routed by blockIdx.x (block-uniform
// branch, so the transpose's __syncthreads is legal).
//   [0,8192):       mem_next = x; kvb = bf16(concat(mem, x))
//   [8192,14336):   weight transposes wq/wkv/wo -> wkvqT/woT
//   [14336,16512):  rel_w -> relb bf16 [h][jp][c] padded
// ---------------------------------------------------------------------------
__global__ __launch_bounds__(256) void prep_all(
    const float* __restrict__ x, const float* __restrict__ mem,
    const float* __restrict__ rel,
    float* __restrict__ mem_next, short* __restrict__ kvb,
    const float* __restrict__ wq, const float* __restrict__ wkv,
    const float* __restrict__ wo, short* __restrict__ wkvqT,
    short* __restrict__ woT, short* __restrict__ relb) {
    __shared__ float tile[32][33];
    const int bx = blockIdx.x;
    const int tid = threadIdx.x;

    if (bx < 8192) {
        // ---- prep_xmem ----
        const size_t gid = (size_t)bx * 256 + tid;
        if (gid < 1048576) {
            const size_t idx = gid * 4;
            float4 v = *(const float4*)(x + idx);
            *(float4*)(mem_next + idx) = v;
            const int b = (int)(idx >> 20);
            const size_t r = idx & 1048575;
            short4 o;
            o.x = f2bf(v.x); o.y = f2bf(v.y); o.z = f2bf(v.z); o.w = f2bf(v.w);
            *(short4*)(kvb + (size_t)b * 2097152 + 1048576 + r) = o;
        } else {
            const size_t idx = (gid - 1048576) * 4;
            float4 v = *(const float4*)(mem + idx);
            const int b = (int)(idx >> 20);
            const size_t r = idx & 1048575;
            short4 o;
            o.x = f2bf(v.x); o.y = f2bf(v.y); o.z = f2bf(v.z); o.w = f2bf(v.w);
            *(short4*)(kvb + (size_t)b * 2097152 + r) = o;
        }
    } else if (bx < 14336) {
        // ---- transpose_w3: i = z*2048 + gy*32 + gx ----
        const int i = bx - 8192;
        const int z = i >> 11;
        const int rem = i & 2047;
        const int gx = rem & 31, gy = rem >> 5;
        const int N = (z == 1) ? 2048 : 1024;
        if (gy * 32 >= N) return;
        const float* w = (z == 0) ? wq : (z == 1) ? wkv : wo;
        short* wT = (z == 0) ? (wkvqT + (size_t)2048 * 1024) : (z == 1) ? wkvqT : woT;
        const int k0 = gx * 32, n0 = gy * 32;
        const int tx = tid & 31, ty = tid >> 5;
        for (int r = ty; r < 32; r += 8)
            tile[r][tx] = w[(size_t)(k0 + r) * N + n0 + tx];
        __syncthreads();
        for (int r = ty; r < 32; r += 8)
            wT[(size_t)(n0 + r) * 1024 + k0 + tx] = f2bf(tile[tx][r]);
    } else {
        // ---- convert_rel: i = gy*136 + gx ----
        const int i = bx - 14336;
        const int gx = i % 136, gy = i / 136;
        const int h = gy;
        const int jp = gx * 16 + (tid >> 4);
        const int c = (tid & 15) << 2;
        float4 v = make_float4(0.f, 0.f, 0.f, 0.f);
        if (jp < JDIM) v = *(const float4*)(rel + ((size_t)jp * H_DIM + h) * DH + c);
        short4 o;
        o.x = f2bf(v.x); o.y = f2bf(v.y); o.z = f2bf(v.z); o.w = f2bf(v.w);
        *(short4*)(relb + ((size_t)h * RELPAD + jp) * DH + c) = o;
    }
}

// ---------------------------------------------------------------------------
// bf16 MFMA GEMM v3: 128x128 tile, BK=32, double-buffered LDS (1 barrier/
// K-iter), 256 threads. CMODE 1 adds an XCD-locality block swizzle (T1):
//   L = by*24+bx; xcd = L&7; m = L>>3; y' = ((m&7)<<3)|xcd; x' = m>>3.
// Under round-robin dispatch (XCD = linear%8), each XCD owns the 8 A-row-
// panels y' == xcd (mod 8) -> per-XCD A footprint 2 MB (L2-fit) instead of
// the whole 16 MB A. Rows alternate mem/x halves (y'&8 = parity of m), so
// the q-tile early-exits stay evenly spread per XCD and per CU. Bijective.
// CMODE 1 (fused kvq): Bt = wkvqT [3072][1024], grid (24, 64).
//   col<1024 -> kb [bh][j][c]; col<2048 -> vTb [bh][c][j];
//   col>=2048 -> qb [bh][i][c] PRE-SCALED by 0.125*log2e, x-half rows only.
// CMODE 2: out = A @ Bt^T + bias -> Cf fp32 [r][n] (no swizzle; B panel
// already L2-resident).
// ---------------------------------------------------------------------------
template <int CMODE>
__global__ __launch_bounds__(256) void mfma_gemm(
    const short* __restrict__ A, const short* __restrict__ Bt,
    const float* __restrict__ bias,
    short* __restrict__ C0, short* __restrict__ C1, short* __restrict__ C2,
    float* __restrict__ Cf) {
    constexpr int K = 1024;
    constexpr int NT = K / 32;  // 32 K-steps
    int bx = blockIdx.x, by = blockIdx.y;
    if (CMODE == 1) {  // XCD-locality swizzle (see header)
        const int L = by * 24 + bx;
        const int xcd = L & 7, m = L >> 3;
        by = ((m & 7) << 3) | xcd;
        bx = m >> 3;
    }
    const int row0 = by << 7, col0 = bx << 7;
    if (CMODE == 1 && col0 >= 2048 && (row0 & 2047) < 1024) return;  // q x mem-rows

    __shared__ short ash[2][128 * 32];
    __shared__ short bsh[2][128 * 32];

    const int tid = threadIdx.x;
    const int w = tid >> 6, lane = tid & 63;
    const int l15 = lane & 15, quad = lane >> 4;
    const int wr = w >> 1, wc = w & 1;

    const int sk = (lane & 3) << 3;
    const short* ap0 = A + (size_t)(row0 + (w << 5) + (lane >> 2)) * K + sk;
    const short* ap1 = ap0 + (size_t)16 * K;
    const short* bp0 = Bt + (size_t)(col0 + (w << 5) + (lane >> 2)) * K + sk;
    const short* bp1 = bp0 + (size_t)16 * K;

    // prologue: stage t=0 into buf 0
    gl_lds16(ap0, ash[0] + (w << 10));
    gl_lds16(ap1, ash[0] + (w << 10) + 512);
    gl_lds16(bp0, bsh[0] + (w << 10));
    gl_lds16(bp1, bsh[0] + (w << 10) + 512);
    __syncthreads();  // drains stage(0)

    floatx4 acc[4][4] = {};

#pragma unroll 2
    for (int t = 0; t < NT; ++t) {
        const int cur = t & 1;
        if (t + 1 < NT) {  // issue stage(t+1) BEFORE compute: full-phase cover
            const int nxt = cur ^ 1;
            const int k1 = (t + 1) << 5;
            gl_lds16(ap0 + k1, ash[nxt] + (w << 10));
            gl_lds16(ap1 + k1, ash[nxt] + (w << 10) + 512);
            gl_lds16(bp0 + k1, bsh[nxt] + (w << 10));
            gl_lds16(bp1 + k1, bsh[nxt] + (w << 10) + 512);
        }

        short8 af[4];
#pragma unroll
        for (int mt = 0; mt < 4; ++mt)
            af[mt] = *(const short8*)&ash[cur][(((wr << 6) + (mt << 4) + l15) << 5) + (quad << 3)];
#pragma unroll
        for (int nt = 0; nt < 4; ++nt) {
            short8 bf = *(const short8*)&bsh[cur][(((wc << 6) + (nt << 4) + l15) << 5) + (quad << 3)];
#pragma unroll
            for (int mt = 0; mt < 4; ++mt)
                acc[mt][nt] = __builtin_amdgcn_mfma_f32_16x16x32_bf16(af[mt], bf, acc[mt][nt], 0, 0, 0);
        }
        __syncthreads();  // drains stage(t+1); publishes buf[nxt]; frees buf[cur]
    }

#pragma unroll
    for (int nt = 0; nt < 4; ++nt) {
        const int col = col0 + (wc << 6) + (nt << 4) + l15;
        float bv = (CMODE == 2) ? bias[col] : 0.f;
#pragma unroll
        for (int mt = 0; mt < 4; ++mt) {
#pragma unroll
            for (int rr = 0; rr < 4; ++rr) {
                const int row = row0 + (wr << 6) + (mt << 4) + (quad << 2) + rr;
                const float val = acc[mt][nt][rr];
                if (CMODE == 1) {
                    int b = row >> 11, j = row & 2047;
                    if (col < 1024) {
                        int h = col >> 6, c = col & 63;
                        C0[(((size_t)b * H_DIM + h) * JDIM + j) * DH + c] = f2bf(val);
                    } else if (col < 2048) {
                        int n2 = col - 1024, h = n2 >> 6, c = n2 & 63;
                        C1[(((size_t)b * H_DIM + h) * DH + c) * JDIM + j] = f2bf(val);
                    } else {
                        int n2 = col - 2048, h = n2 >> 6, c = n2 & 63;
                        int i = j - 1024;  // guaranteed >= 0 by early-exit
                        // pre-scale q by 0.125 * log2(e): QK^T and rel-G come
                        // out of MFMA already in the exp2 domain
                        C2[(((size_t)b * H_DIM + h) * T_DIM + i) * DH + c] =
                            f2bf(val * 0.18033688f);
                    }
                } else {
                    Cf[(size_t)row * 1024 + col] = val + bv;
                }
            }
        }
    }
}

// ---------------------------------------------------------------------------
// Flash attention v10: v9 pipeline (2 barriers/iter, K/V single-buffer +
// mod-3 rel ring, psh overlaid in dead s0 slot w/ XOR swizzle, prescaled q,
// defer-max, setprio, v_perm, 40 KB LDS -> 4 blocks/CU) with an
// XCD-locality block map (T1) replacing the round-6 hash:
//   L = by*16+bx; xcd = L&7; m = L>>3; bh = ((m&7)<<3)|xcd; itile = m>>3.
// Each XCD owns bh == xcd (mod 8): 8 bh (4 MB K/V) and only 2 distinct h
// (0.56 MB rel) -> L2-resident working set, vs all-64-bh thrash (measured
// FETCH 175 MB vs ~47 ideal). Per-CU balance preserved: co-resident blocks
// {L, L+256, L+512, L+768} get itiles {t, t+4, t+8, t+12} (same multiset as
// the round-6 map). Bijective: (bh,itile) <- (L) is a bit permutation.
// ---------------------------------------------------------------------------
__global__ __launch_bounds__(256, 4) void flash_attn(
    const short* __restrict__ qb, const short* __restrict__ kb,
    const short* __restrict__ vTb, const short* __restrict__ relb,
    short* __restrict__ ob) {
    __shared__ short kshf[8 * 512];       // 8 KB
    __shared__ short vshf[8 * 512];       // 8 KB
    __shared__ short rshf[3 * 8 * 512];   // 24 KB, 3-seg ring (64 rows/seg);
                                          // psh overlays the dead s0 slot

    const int tid = threadIdx.x;
    const int w = tid >> 6;
    const int lane = tid & 63;
    const int l15 = lane & 15, quad = lane >> 4;
    // XCD-locality map (see header)
    const int L = blockIdx.y * 16 + blockIdx.x;
    const int xcd = L & 7, m = L >> 3;
    const int bh = ((m & 7) << 3) | xcd;
    const int itile = m >> 3;
    const int h = bh & 15, b = bh >> 4;
    const int i0 = itile << 6;
    const int goff = 3 - w;

    const short* kb_b = kb + (size_t)bh * JDIM * DH;
    const short* vT_b = vTb + (size_t)bh * DH * JDIM;
    const short* rel_b = relb + (size_t)h * RELPAD * DH;

    // Q fragments straight from global (pre-scaled by 0.125*log2e)
    const short* qrow = qb + ((size_t)bh * T_DIM + i0 + (w << 4) + l15) * DH;
    const short8 a_q0 = *(const short8*)(qrow + (quad << 3));
    const short8 a_q1 = *(const short8*)(qrow + 32 + (quad << 3));

    // staging pointers: wave w owns chunks {w, w+4} of each tile
    const int kc0 = w, kc1 = w + 4;
    const short* kp0 = kb_b + (size_t)(((kc0 >> 1) << 4) + l15) * DH + (kc0 & 1) * 32 + (quad << 3);
    const short* kp1 = kb_b + (size_t)(((kc1 >> 1) << 4) + l15) * DH + (kc1 & 1) * 32 + (quad << 3);
    const short* vp0 = vT_b + (size_t)(((kc0 >> 1) << 4) + l15) * JDIM + (kc0 & 1) * 32 + (quad << 3);
    const short* vp1 = vT_b + (size_t)(((kc1 >> 1) << 4) + l15) * JDIM + (kc1 & 1) * 32 + (quad << 3);
    const int base00 = 960 - i0;  // >= 0

    // ---- prologue: K(0), V(0), rel segs 0,1 (128 rows) ----
    gl_lds16(kp0, kshf + (kc0 << 9));
    gl_lds16(kp1, kshf + (kc1 << 9));
    gl_lds16(vp0, vshf + (kc0 << 9));
    gl_lds16(vp1, vshf + (kc1 << 9));
    kp0 += 64 * DH; kp1 += 64 * DH; vp0 += 64; vp1 += 64;
#pragma unroll
    for (int s = 0; s < 4; ++s) {
        const int c4 = w + (s << 2);  // chunk over segs 0..1 (contiguous)
        const short* rp = rel_b + (size_t)(base00 + ((c4 >> 1) << 4) + l15) * DH +
                          (c4 & 1) * 32 + (quad << 3);
        gl_lds16(rp, rshf + (c4 << 9));
    }
    // steady-state rel write pointers (rows base0+128.., chunks w, w+4 of seg s2)
    const short* rw0 = rel_b + (size_t)(base00 + 128 + ((w >> 1) << 4) + l15) * DH +
                       (w & 1) * 32 + (quad << 3);
    const short* rw1 = rel_b + (size_t)(base00 + 128 + (((w + 4) >> 1) << 4) + l15) * DH +
                       ((w + 4) & 1) * 32 + (quad << 3);
    __syncthreads();  // drain prologue

    // all-ones B fragment for row-sum MFMA
    short8 ones8;
#pragma unroll
    for (int z = 0; z < 8; ++z) ones8[z] = (short)0x3F80;

    // gather controls: source lane + v_perm selector
    int srcl[4];
    uint32_t psel[4];
#pragma unroll
    for (int r = 0; r < 4; ++r) {
        const int t = l15 - (quad << 2) - r + 15;
        psel[r] = (t >> 4) ? 0x01000404u : 0x03020404u;
        srcl[r] = (quad << 4) | (t & 15);
    }

    floatx4 o_acc[4] = {};
    float m_r[4], l_r[4];
#pragma unroll
    for (int r = 0; r < 4; ++r) { m_r[r] = -3.0e38f; l_r[r] = 0.f; }

    const int jt_end = itile + 17;
    int s0 = 0, s1 = 1, s2 = 2;    // ring segs: jt, jt+1, prefetch target

    for (int jt = 0; jt < jt_end; ++jt) {
        // ---- QK^T + banded rel (MFMA cluster, prio-boosted) ----
        __builtin_amdgcn_s_setprio(1);
        floatx4 s_acc[4];
#pragma unroll
        for (int nt = 0; nt < 4; ++nt) {
            short8 bk0 = *(const short8*)&kshf[((nt << 1) << 9) + (lane << 3)];
            short8 bk1 = *(const short8*)&kshf[(((nt << 1) + 1) << 9) + (lane << 3)];
            floatx4 acc = {0.f, 0.f, 0.f, 0.f};
            acc = __builtin_amdgcn_mfma_f32_16x16x32_bf16(a_q0, bk0, acc, 0, 0, 0);
            acc = __builtin_amdgcn_mfma_f32_16x16x32_bf16(a_q1, bk1, acc, 0, 0, 0);
            s_acc[nt] = acc;
        }

        // G blocks rb = gi+goff, gi in [0,5); ring seg by rb>=4
        floatx4 G[5];
#pragma unroll
        for (int gi = 0; gi < 5; ++gi) {
            const int rb = gi + goff;
            const int seg = (rb & 4) ? s1 : s0;
            const int ch = (seg << 3) + ((rb & 3) << 1);
            short8 br0 = *(const short8*)&rshf[(ch << 9) + (lane << 3)];
            short8 br1 = *(const short8*)&rshf[((ch + 1) << 9) + (lane << 3)];
            floatx4 acc = {0.f, 0.f, 0.f, 0.f};
            acc = __builtin_amdgcn_mfma_f32_16x16x32_bf16(a_q0, br0, acc, 0, 0, 0);
            G[gi] = __builtin_amdgcn_mfma_f32_16x16x32_bf16(a_q1, br1, acc, 0, 0, 0);
        }
        __builtin_amdgcn_s_setprio(0);

        // ---- pack + gather shifted rel (v_perm: 1 op each) ----
        uint32_t pk[4][4];
#pragma unroll
        for (int gi = 0; gi < 4; ++gi)
#pragma unroll
            for (int r = 0; r < 4; ++r)
                pk[gi][r] = __builtin_amdgcn_perm(
                    __builtin_bit_cast(uint32_t, G[gi][r]),
                    __builtin_bit_cast(uint32_t, G[gi + 1][r]), 0x07060302u);
#pragma unroll
        for (int nt = 0; nt < 4; ++nt)
#pragma unroll
            for (int r = 0; r < 4; ++r) {
                uint32_t pv = (uint32_t)__shfl((int)pk[nt][r], srcl[r], 64);
                uint32_t gb = __builtin_amdgcn_perm(0u, pv, psel[r]);
                s_acc[nt][r] = s_acc[nt][r] + __builtin_bit_cast(float, gb);
            }
        if (jt == jt_end - 1) {  // triangular mask: valid iff u <= v
#pragma unroll
            for (int nt = 0; nt < 4; ++nt) {
                const int u = (nt << 4) + l15;
#pragma unroll
                for (int r = 0; r < 4; ++r) {
                    const int v = (w << 4) + (quad << 2) + r;
                    if (u > v) s_acc[nt][r] = -3.0e38f;
                }
            }
        }

        __syncthreads();  // b1: drains V(jt); seg s0 rel data now dead -> psh
        if (jt + 1 < jt_end) {  // prefetch K(jt+1), rel seg s2 (drained at b2)
            gl_lds16(kp0, kshf + (kc0 << 9));
            gl_lds16(kp1, kshf + (kc1 << 9));
            gl_lds16(rw0, rshf + (s2 << 12) + (w << 9));
            gl_lds16(rw1, rshf + (s2 << 12) + ((w + 4) << 9));
            kp0 += 64 * DH; kp1 += 64 * DH; rw0 += 64 * DH; rw1 += 64 * DH;
        }

        // psh lives in the dead s0 slot this iteration (wave-private rows)
        short* pshp = rshf + (s0 << 12);

        // ---- online softmax with defer-max (THR=8) ----
        float tm[4];
        bool need = false;
#pragma unroll
        for (int r = 0; r < 4; ++r) {
            tm[r] = fmaxf(fmaxf(s_acc[0][r], s_acc[1][r]),
                          fmaxf(s_acc[2][r], s_acc[3][r]));
            need |= (tm[r] > m_r[r] + 8.0f);
        }
        if (__any((int)need)) {
#pragma unroll
            for (int r = 0; r < 4; ++r) {
                const float t = row16_max(tm[r]);
                const float mx = fmaxf(m_r[r], t);
                const float alpha = __builtin_amdgcn_exp2f(m_r[r] - mx);
                m_r[r] = mx;
                l_r[r] *= alpha;
#pragma unroll
                for (int ct = 0; ct < 4; ++ct) o_acc[ct][r] *= alpha;
            }
        }
#pragma unroll
        for (int r = 0; r < 4; ++r) {
            const int prow = (w << 4) + (quad << 2) + r;
            char* rowb = (char*)pshp + (prow << 7);   // 128 B row stride
            const int swz = (prow & 7) << 4;          // XOR bank swizzle
#pragma unroll
            for (int nt = 0; nt < 4; ++nt) {
                const float p = __builtin_amdgcn_exp2f(s_acc[nt][r] - m_r[r]);
                *(short*)(rowb + ((((nt << 5) + (l15 << 1))) ^ swz)) = f2bf(p);
            }
        }

        // ---- PV + row-sum (MFMA cluster, prio-boosted; V(jt) drained at b1)
        const int arow = (w << 4) + l15;
        const char* arowb = (const char*)pshp + (arow << 7);
        const int asw = (l15 & 7) << 4;
        const short8 a_p0 = *(const short8*)(arowb + ((quad << 4) ^ asw));
        const short8 a_p1 = *(const short8*)(arowb + ((64 + (quad << 4)) ^ asw));
        __builtin_amdgcn_s_setprio(1);
        floatx4 ls = {0.f, 0.f, 0.f, 0.f};
        ls = __builtin_amdgcn_mfma_f32_16x16x32_bf16(a_p0, ones8, ls, 0, 0, 0);
        ls = __builtin_amdgcn_mfma_f32_16x16x32_bf16(a_p1, ones8, ls, 0, 0, 0);
#pragma unroll
        for (int r = 0; r < 4; ++r) l_r[r] += ls[r];
#pragma unroll
        for (int ct = 0; ct < 4; ++ct) {
            short8 bv0 = *(const short8*)&vshf[((ct << 1) << 9) + (lane << 3)];
            short8 bv1 = *(const short8*)&vshf[(((ct << 1) + 1) << 9) + (lane << 3)];
            o_acc[ct] = __builtin_amdgcn_mfma_f32_16x16x32_bf16(a_p0, bv0, o_acc[ct], 0, 0, 0);
            o_acc[ct] = __builtin_amdgcn_mfma_f32_16x16x32_bf16(a_p1, bv1, o_acc[ct], 0, 0, 0);
        }
        __builtin_amdgcn_s_setprio(0);

        __syncthreads();  // b2: drains K(jt+1)/rel; V buffer free; psh dead
        if (jt + 1 < jt_end) {  // prefetch V(jt+1) (drained at b1 of jt+1)
            gl_lds16(vp0, vshf + (kc0 << 9));
            gl_lds16(vp1, vshf + (kc1 << 9));
            vp0 += 64; vp1 += 64;
        }
        const int t = s0; s0 = s1; s1 = s2; s2 = t;  // rotate ring
    }

    // ---- epilogue: normalize, write ob bf16 [b][i][d] ----
#pragma unroll
    for (int ct = 0; ct < 4; ++ct) {
#pragma unroll
        for (int r = 0; r < 4; ++r) {
            const int i = i0 + (w << 4) + (quad << 2) + r;
            const float val = o_acc[ct][r] / l_r[r];
            ob[((size_t)b * T_DIM + i) * D_DIM + h * DH + (ct << 4) + l15] = f2bf(val);
        }
    }
}

// ---------------------------------------------------------------------------
extern "C" void kernel_launch(void* const* d_in, const int* in_sizes, int n_in,
                              void* d_out, int out_size, void* d_ws, size_t ws_size,
                              hipStream_t stream) {
    const float* x = (const float*)d_in[0];
    const float* mem = (const float*)d_in[1];
    const float* wq = (const float*)d_in[2];
    const float* wkv = (const float*)d_in[3];
    const float* wo = (const float*)d_in[4];
    const float* bo = (const float*)d_in[5];
    const float* rel_w = (const float*)d_in[6];

    float* out = (float*)d_out;
    float* mem_next = out + (size_t)B_DIM * T_DIM * D_DIM;

    // workspace layout (shorts), ~80 MB total
    short* kvb = (short*)d_ws;       // 8,388,608  [b][j][d] bf16
    short* qb = kvb + 8388608;       // 4,194,304  [bh][i][c]
    short* kb = qb + 4194304;        // 8,388,608  [bh][j][c]
    short* vTb = kb + 8388608;       // 8,388,608  [bh][c][j]
    short* relb = vTb + 8388608;     // 2,228,224  [h][jp][c]
    short* ob = relb + 2228224;      // 4,194,304  [b*i][d]
    short* wkvqT = ob + 4194304;     // 3,145,728  [3072][1024]
    short* woT = wkvqT + 3145728;    // 1,048,576  [1024][1024]

    // merged prep: mem_next/kvb + weight transposes + rel conversion
    hipLaunchKernelGGL(prep_all, dim3(16512), dim3(256), 0, stream,
                       x, mem, rel_w, mem_next, kvb, wq, wkv, wo,
                       wkvqT, woT, relb);

    // fused kvq GEMM: kvin @ [wkv|wq] -> kb, vTb, qb
    hipLaunchKernelGGL((mfma_gemm<1>), dim3(24, 64), dim3(256), 0, stream,
                       kvb, wkvqT, nullptr, kb, vTb, qb, nullptr);

    // flash attention -> ob bf16
    hipLaunchKernelGGL(flash_attn, dim3(16, 64), dim3(256), 0, stream,
                       qb, kb, vTb, relb, ob);

    // out = ob @ wo + bo -> fp32
    hipLaunchKernelGGL((mfma_gemm<2>), dim3(8, 32), dim3(256), 0, stream,
                       ob, woT, bo, nullptr, nullptr, nullptr, out);
}